// Round 4
// baseline (288.471 us; speedup 1.0000x reference)
//
#include <hip/hip_runtime.h>
#include <cstddef>

// RNN: h_t = tanh(x_t @ W_ih^T + b_ih + h_{t-1} @ W_hh^T + b_hh), return h_T.
// B=4096, T=512, IN=15, H=20.
//
// R2 post-mortem: DS-queue reordering + swizzle (conflicts 524k->0) moved
// nothing (103.5->109.2us). The recurrence was still gated by lgkmcnt(0)
// (newest queue entry consumed first), and the LDS h round-trip (~130cy) +
// serial dot chain is the structural floor of any lane=hidden-unit layout.
//
// R3: MFMA reformulation -- h never leaves registers.
//   h_new[j][b] = tanh(Whh[j][:]·h[:][b] + cx[j][b]) as two PARALLEL
//   v_mfma_f32_16x16x32_f16 (M-split over j, N=16 batches/wave, K=32>=20).
//   Row permutation sigma_P(m)=8*(m>>2)+(m&3), sigma_Q=+4 applied to the
//   A-fragment rows makes D's per-lane-group output {8G+r} / {8G+4+r} ==
//   exactly the k-window [8G,8G+8) the next step's B-operand needs in that
//   lane group: D -> (8x tanh + 4x cvt_pkrtz) -> B, zero cross-lane ops.
//   x-projection: off-chain legacy v_mfma_f32_16x16x16f16 (K=16>=15, no
//   underscore in the builtin name -- R3 compile fix), computed one step
//   ahead with C = pre-scaled bias; x f16-staged in LDS (chunked,
//   double-buffered), 1 prefetched ds_read_b64/step, off critical path.
//   R4 compile fix: cvt_pkrtz returns __fp16x2; bit_cast to _Float16x2.
//   Weights/bias pre-scaled by 2*log2(e); tanh = 1 - 2*rcp(1+exp2(s)).
// Chain/step ~ mfma(25) + tanh(25) + pack(8); issue ~130cy -> ~35-55us.
// Fragment layouts (16x16x32: A/B lane l: m|n=l&15, k=8*(l>>4)+i;
// D: n=l&15, m=4*(l>>4)+r. 16x16x16: k=4*(l>>4)+i) per verified m89/m92/m97.

typedef float f4 __attribute__((ext_vector_type(4)));
typedef float g4 __attribute__((ext_vector_type(4), aligned(4)));
typedef _Float16 h2 __attribute__((ext_vector_type(2)));
typedef _Float16 v4h __attribute__((ext_vector_type(4)));
typedef _Float16 v8h __attribute__((ext_vector_type(8)));
typedef __fp16 p2 __attribute__((ext_vector_type(2)));

#define TT 512
#define IN 15
#define HD 20
#define NB 16              // batches per wave
#define CT 16              // timesteps per staged chunk
#define NC (TT / CT)       // 32 chunks
#define XCHUNK (CT * 256)  // halves per chunk buffer (512B per t)

__device__ __forceinline__ h2 pk2(float a, float b) {
  p2 r = __builtin_amdgcn_cvt_pkrtz(a, b);
  return __builtin_bit_cast(h2, r);
}
__device__ __forceinline__ v4h cat4(h2 a, h2 b) {
  return __builtin_shufflevector(a, b, 0, 1, 2, 3);
}
__device__ __forceinline__ v8h cat8(v4h a, v4h b) {
  return __builtin_shufflevector(a, b, 0, 1, 2, 3, 4, 5, 6, 7);
}

__global__ __launch_bounds__(64) void rnn_mfma(
    const float* __restrict__ feature, const float* __restrict__ W_ih,
    const float* __restrict__ W_hh, const float* __restrict__ b_ih,
    const float* __restrict__ b_hh, float* __restrict__ out, int B) {
  // x staged as f16 B-fragments: per t, 64 lane-slots of 4 halves (512B/t).
  __shared__ __align__(16) _Float16 xh[2 * XCHUNK];

  const int l = threadIdx.x;   // 0..63
  const int G = l >> 4;        // k-group 0..3
  const int mf = l & 15;       // A fragment row / B,D batch column
  const int b0 = blockIdx.x * NB;

  const float K2 = 2.8853900817779268f;  // 2*log2(e), folded into weights

  // --- weight fragments with sigma row permutation -------------------
  const int jPa = 8 * (mf >> 2) + (mf & 3);  // sigma_P(frag row)
  const int jQa = jPa + 4;                   // sigma_Q

  v8h AhhP, AhhQ;  // 16x16x32: lane holds k = 8G+i, i=0..7
#pragma unroll
  for (int i = 0; i < 8; ++i) {
    const int k = 8 * G + i;
    AhhP[i] = (_Float16)((jPa < HD && k < HD) ? K2 * W_hh[jPa * HD + k] : 0.f);
    AhhQ[i] = (_Float16)((jQa < HD && k < HD) ? K2 * W_hh[jQa * HD + k] : 0.f);
  }
  v4h AihP, AihQ;  // 16x16x16: lane holds k = 4G+i, i=0..3
#pragma unroll
  for (int i = 0; i < 4; ++i) {
    const int k = 4 * G + i;
    AihP[i] = (_Float16)((jPa < HD && k < IN) ? K2 * W_ih[jPa * IN + k] : 0.f);
    AihQ[i] = (_Float16)((jQa < HD && k < IN) ? K2 * W_ih[jQa * IN + k] : 0.f);
  }
  // bias as C fragments: row m = 4G+r -> j = 8G+r (P) / 8G+4+r (Q)
  f4 biasP, biasQ;
#pragma unroll
  for (int r = 0; r < 4; ++r) {
    const int jp = 8 * G + r, jq = jp + 4;
    biasP[r] = (jp < HD) ? K2 * (b_ih[jp] + b_hh[jp]) : 0.f;
    biasQ[r] = (jq < HD) ? K2 * (b_ih[jq] + b_hh[jq]) : 0.f;
  }

  // --- x staging: chunk of CT t's, 256 rows (16 b x 16 t), 4 rows/lane ---
  const int sc = l >> 2;  // batch col this lane stages
  const int st = l & 3;   // t sub-index
  const float* srow = feature + (size_t)min(b0 + sc, B - 1) * TT * IN;
  g4 R0[4], R1[4], R2[4], R3[4];

  auto issue = [&](int ch) {  // coalesced-ish global loads into regs
    const int t0 = ch * CT;
#pragma unroll
    for (int q = 0; q < 4; ++q) {
      const float* s = srow + (size_t)(t0 + st + 4 * q) * IN;
      R0[q] = *(const g4*)s;        // f0..f3
      R1[q] = *(const g4*)(s + 4);  // f4..f7
      R2[q] = *(const g4*)(s + 8);  // f8..f11
      R3[q] = *(const g4*)(s + 11); // f11..f14 (overlap)
    }
  };
  auto commit = [&](int ch) {  // f32 regs -> f16 lane-slot layout in LDS
    _Float16* base = xh + (ch & 1) * XCHUNK + sc * 4;
#pragma unroll
    for (int q = 0; q < 4; ++q) {
      _Float16* row = base + (st + 4 * q) * 256;  // G-slot stride 64 halves
      *(v4h*)(row)       = cat4(pk2(R0[q].x, R0[q].y), pk2(R0[q].z, R0[q].w));
      *(v4h*)(row + 64)  = cat4(pk2(R1[q].x, R1[q].y), pk2(R1[q].z, R1[q].w));
      *(v4h*)(row + 128) = cat4(pk2(R2[q].x, R2[q].y), pk2(R2[q].z, R2[q].w));
      *(v4h*)(row + 192) = cat4(pk2(R3[q].y, R3[q].z), pk2(R3[q].w, 0.f));
    }
  };

  issue(0);
  commit(0);

  // prologue: cx(0) from x(0); Xc holds x(1); first reads land via in-order DS
  v4h Xc = *(const v4h*)(xh + l * 4);  // x(0)
  f4 cxPc = __builtin_amdgcn_mfma_f32_16x16x16f16(AihP, Xc, biasP, 0, 0, 0);
  f4 cxQc = __builtin_amdgcn_mfma_f32_16x16x16f16(AihQ, Xc, biasQ, 0, 0, 0);
  Xc = *(const v4h*)(xh + 256 + l * 4);  // x(1)
  int xoff = 2 * 256 + l * 4;            // next read: t=2 (halves)

  v8h Bh;  // h_{t-1} B-fragment; h0 = 0
#pragma unroll
  for (int i = 0; i < 8; ++i) Bh[i] = (_Float16)0.f;

  float tPk[4], tQk[4];  // last tanh values (f32) -> final store

  for (int ch = 0; ch < NC; ++ch) {
    if (ch + 1 < NC) issue(ch + 1);  // global prefetch, consumed at tc==8
#pragma unroll
    for (int tc = 0; tc < CT; ++tc) {
      if (tc == 8 && ch + 1 < NC) {
        commit(ch + 1);  // LDS write >= 2 steps before first read (in-order DS)
        asm volatile("" ::: "memory");
      }
      // --- recurrence chain: mfma -> tanh -> pack -> mfma ---
      f4 aP = __builtin_amdgcn_mfma_f32_16x16x32_f16(AhhP, Bh, cxPc, 0, 0, 0);
      f4 aQ = __builtin_amdgcn_mfma_f32_16x16x32_f16(AhhQ, Bh, cxQc, 0, 0, 0);
      // off-chain: x-frag prefetch (t+2) and x-projection (t+1)
      v4h Xn = *(const v4h*)(xh + xoff);
      xoff = (xoff + 256) & (2 * XCHUNK - 1);
      cxPc = __builtin_amdgcn_mfma_f32_16x16x16f16(AihP, Xc, biasP, 0, 0, 0);
      cxQc = __builtin_amdgcn_mfma_f32_16x16x16f16(AihQ, Xc, biasQ, 0, 0, 0);
      Xc = Xn;
      // tanh(s) with s pre-scaled by 2*log2(e): 1 - 2/(1+2^s)
#pragma unroll
      for (int r = 0; r < 4; ++r) {
        const float eP = exp2f(aP[r]);
        tPk[r] = 1.f - 2.f * __builtin_amdgcn_rcpf(1.f + eP);
        const float eQ = exp2f(aQ[r]);
        tQk[r] = 1.f - 2.f * __builtin_amdgcn_rcpf(1.f + eQ);
      }
      Bh = cat8(cat4(pk2(tPk[0], tPk[1]), pk2(tPk[2], tPk[3])),
                cat4(pk2(tQk[0], tQk[1]), pk2(tQk[2], tQk[3])));
    }
  }

  // epilogue: lane holds h_T[8G+r] (P) and h_T[8G+4+r] (Q) for batch b0+mf
  const int batch = b0 + mf;
  if (batch < B) {
    float* orow = out + (size_t)batch * HD;
#pragma unroll
    for (int r = 0; r < 4; ++r) {
      const int jp = 8 * G + r;
      if (jp < HD) orow[jp] = tPk[r];
      const int jq = jp + 4;
      if (jq < HD) orow[jq] = tQk[r];
    }
  }
}

extern "C" void kernel_launch(void* const* d_in, const int* in_sizes, int n_in,
                              void* d_out, int out_size, void* d_ws, size_t ws_size,
                              hipStream_t stream) {
  const float* feature = (const float*)d_in[0];
  const float* W_ih    = (const float*)d_in[1];
  const float* W_hh    = (const float*)d_in[2];
  const float* b_ih    = (const float*)d_in[3];
  const float* b_hh    = (const float*)d_in[4];
  float* out = (float*)d_out;
  const int B = in_sizes[0] / (TT * IN);        // 4096
  const int grid = (B + NB - 1) / NB;           // 16 batches per 64-thread wave
  rnn_mfma<<<grid, 64, 0, stream>>>(feature, W_ih, W_hh, b_ih, b_hh, out, B);
}

// Round 6
// 230.272 us; speedup vs baseline: 1.2527x; 1.2527x over previous
//
#include <hip/hip_runtime.h>
#include <cstddef>

// RNN: h_t = tanh(x_t @ W_ih^T + b_ih + h_{t-1} @ W_hh^T + b_hh), return h_T.
// B=4096, T=512, IN=15, H=20.
//
// R4 post-mortem: MFMA recurrence passed (sigma-permutation layout verified
// by refcheck) but 729 cyc/step with ~600 cyc STALL. Causes: (a) issue()
// held 64 VGPRs of staged x -> compiler sank loads into commit -> ~900cy
// vmcnt(0) drain inside the serial window; (b) per-step ds_read issued
// before its consumer's lgkmcnt -> ~120cy over-wait; (c) 1.57M LDS bank
// conflicts in commit. Root cause: x staging through LDS is dead weight.
//
// R5: NO LDS AT ALL. Each lane's cx B-fragment (x[b][t][4G..4G+3], 16B)
// is global_load_dwordx4'd directly into a depth-8 register pipeline,
// consumed 8 steps (~2000cy) after issue -> counted vmcnt waits, no drains.
// G=3 would need k=12..15 (k=15 reads 4B past buffer at the last element),
// so G=3 loads k=11..14 and the duplicate k=11 weight in G=2 is zeroed --
// the A-fragment absorbs the shift. exp2 forced native (v_exp_f32).
// Chain/step: mfma(~50) + 8exp+8rcp trans issue(~130) + pack(~25) ~ 250cy.
// (R5 resubmit unchanged: previous round was an infra failure, kernel
// never executed.)
//
// Recurrence (verified R4): h in registers through the matrix pipe.
//   Two parallel v_mfma_f32_16x16x32_f16 (M-split over j, N=16 batches).
//   Row perm sigma_P(m)=8*(m>>2)+(m&3), sigma_Q=+4 makes D's lane-group
//   output {8G+r}/{8G+4+r} exactly the k-window [8G,8G+8) the next B
//   fragment needs in-lane: D -> 8 tanh + 6 pack -> B, zero cross-lane.
//   x-projection: off-chain v_mfma_f32_16x16x16f16, one step ahead,
//   C = pre-scaled bias. Weights/bias pre-scaled by 2*log2(e);
//   tanh = 1 - 2*rcp(1+exp2(s)).

typedef float f4 __attribute__((ext_vector_type(4)));
typedef float g4 __attribute__((ext_vector_type(4), aligned(4)));
typedef _Float16 h2 __attribute__((ext_vector_type(2)));
typedef _Float16 v4h __attribute__((ext_vector_type(4)));
typedef _Float16 v8h __attribute__((ext_vector_type(8)));
typedef __fp16 p2 __attribute__((ext_vector_type(2)));

#define TT 512
#define IN 15
#define HD 20
#define NB 16  // batches per wave

__device__ __forceinline__ float fexp2(float x) {
#if __has_builtin(__builtin_amdgcn_exp2f)
  return __builtin_amdgcn_exp2f(x);  // native v_exp_f32
#else
  return exp2f(x);
#endif
}
__device__ __forceinline__ h2 pk2(float a, float b) {
  p2 r = __builtin_amdgcn_cvt_pkrtz(a, b);
  return __builtin_bit_cast(h2, r);
}
__device__ __forceinline__ v4h cat4(h2 a, h2 b) {
  return __builtin_shufflevector(a, b, 0, 1, 2, 3);
}
__device__ __forceinline__ v8h cat8(v4h a, v4h b) {
  return __builtin_shufflevector(a, b, 0, 1, 2, 3, 4, 5, 6, 7);
}

__global__ __launch_bounds__(64) void rnn_mfma(
    const float* __restrict__ feature, const float* __restrict__ W_ih,
    const float* __restrict__ W_hh, const float* __restrict__ b_ih,
    const float* __restrict__ b_hh, float* __restrict__ out, int B) {
  const int l = threadIdx.x;   // 0..63
  const int G = l >> 4;        // k-group 0..3
  const int mf = l & 15;       // A fragment row / B,D batch column
  const int b0 = blockIdx.x * NB;

  const float K2 = 2.8853900817779268f;  // 2*log2(e), folded into weights

  // --- weight fragments with sigma row permutation -------------------
  const int jPa = 8 * (mf >> 2) + (mf & 3);  // sigma_P(frag row)
  const int jQa = jPa + 4;                   // sigma_Q

  v8h AhhP, AhhQ;  // 16x16x32: lane holds k = 8G+i, i=0..7
#pragma unroll
  for (int i = 0; i < 8; ++i) {
    const int k = 8 * G + i;
    AhhP[i] = (_Float16)((jPa < HD && k < HD) ? K2 * W_hh[jPa * HD + k] : 0.f);
    AhhQ[i] = (_Float16)((jQa < HD && k < HD) ? K2 * W_hh[jQa * HD + k] : 0.f);
  }
  // 16x16x16 A for x-projection. Lane's data window: G<3 -> k0=4G (k=4G..
  // 4G+3); G=3 -> k0=11 (k=11..14, avoids reading past buffer end at the
  // very last row). k=11 appears in both G=2 and G=3: zero it in G=2.
  const int k0 = (G < 3) ? 4 * G : 11;
  v4h AihP, AihQ;
#pragma unroll
  for (int i = 0; i < 4; ++i) {
    const int k = k0 + i;
    const bool dup = (G == 2 && i == 3);  // k=11 owned by G=3
    AihP[i] = (_Float16)((jPa < HD && k < IN && !dup) ? K2 * W_ih[jPa * IN + k]
                                                      : 0.f);
    AihQ[i] = (_Float16)((jQa < HD && k < IN && !dup) ? K2 * W_ih[jQa * IN + k]
                                                      : 0.f);
  }
  // bias as C fragments: row m = 4G+r -> j = 8G+r (P) / 8G+4+r (Q)
  f4 biasP, biasQ;
#pragma unroll
  for (int r = 0; r < 4; ++r) {
    const int jp = 8 * G + r, jq = jp + 4;
    biasP[r] = (jp < HD) ? K2 * (b_ih[jp] + b_hh[jp]) : 0.f;
    biasQ[r] = (jq < HD) ? K2 * (b_ih[jq] + b_hh[jq]) : 0.f;
  }

  // --- per-lane x fragment source: 16B at feature[b][t][k0] ----------
  const int b = min(b0 + mf, B - 1);
  const float* xbase = feature + (size_t)b * TT * IN + k0;
  auto load_x = [&](int t) -> g4 {
    return *(const g4*)(xbase + (size_t)t * IN);
  };

  // depth-8 register pipeline: slot s holds x(t) with t ≡ s (mod 8),
  // consumed 8 steps after issue (static indices only -- rule #20).
  g4 XR[8];
#pragma unroll
  for (int s = 1; s <= 8; ++s) XR[s & 7] = load_x(s);

  // prologue: cx(0)
  g4 x0 = load_x(0);
  v4h X0 = cat4(pk2(x0.x, x0.y), pk2(x0.z, x0.w));
  f4 cxPc = __builtin_amdgcn_mfma_f32_16x16x16f16(AihP, X0, biasP, 0, 0, 0);
  f4 cxQc = __builtin_amdgcn_mfma_f32_16x16x16f16(AihQ, X0, biasQ, 0, 0, 0);

  v8h Bh;  // h_t B-fragment; h0 = 0
#pragma unroll
  for (int i = 0; i < 8; ++i) Bh[i] = (_Float16)0.f;

  float tPk[4], tQk[4];  // last tanh values (f32) -> final store

  for (int t = 0; t < TT; t += 8) {
#pragma unroll
    for (int u = 0; u < 8; ++u) {
      // --- recurrence chain: mfma -> tanh -> pack -> mfma ---
      f4 aP = __builtin_amdgcn_mfma_f32_16x16x32_f16(AhhP, Bh, cxPc, 0, 0, 0);
      f4 aQ = __builtin_amdgcn_mfma_f32_16x16x32_f16(AhhQ, Bh, cxQc, 0, 0, 0);
      // off-chain: cx(t+u+1) from pipeline slot (loaded 8 steps ago)
      const int s = (u + 1) & 7;
      g4 xr = XR[s];
      v4h Xn = cat4(pk2(xr.x, xr.y), pk2(xr.z, xr.w));
      cxPc = __builtin_amdgcn_mfma_f32_16x16x16f16(AihP, Xn, biasP, 0, 0, 0);
      cxQc = __builtin_amdgcn_mfma_f32_16x16x16f16(AihQ, Xn, biasQ, 0, 0, 0);
      // refill slot with x(t+u+9) (clamped tail loads are harmless)
      const int tn = t + u + 9;
      XR[s] = load_x(tn < TT ? tn : TT - 1);
      // tanh(s) with s pre-scaled by 2*log2(e): 1 - 2/(1+2^s)
#pragma unroll
      for (int r = 0; r < 4; ++r) {
        const float eP = fexp2(aP[r]);
        tPk[r] = 1.f - 2.f * __builtin_amdgcn_rcpf(1.f + eP);
        const float eQ = fexp2(aQ[r]);
        tQk[r] = 1.f - 2.f * __builtin_amdgcn_rcpf(1.f + eQ);
      }
      Bh = cat8(cat4(pk2(tPk[0], tPk[1]), pk2(tPk[2], tPk[3])),
                cat4(pk2(tQk[0], tQk[1]), pk2(tQk[2], tQk[3])));
    }
  }

  // epilogue: lane holds h_T[8G+r] (P) and h_T[8G+4+r] (Q) for batch b0+mf
  const int batch = b0 + mf;
  if (batch < B) {
    float* orow = out + (size_t)batch * HD;
#pragma unroll
    for (int r = 0; r < 4; ++r) {
      const int jp = 8 * G + r;
      if (jp < HD) orow[jp] = tPk[r];
      const int jq = jp + 4;
      if (jq < HD) orow[jq] = tQk[r];
    }
  }
}

extern "C" void kernel_launch(void* const* d_in, const int* in_sizes, int n_in,
                              void* d_out, int out_size, void* d_ws, size_t ws_size,
                              hipStream_t stream) {
  const float* feature = (const float*)d_in[0];
  const float* W_ih    = (const float*)d_in[1];
  const float* W_hh    = (const float*)d_in[2];
  const float* b_ih    = (const float*)d_in[3];
  const float* b_hh    = (const float*)d_in[4];
  float* out = (float*)d_out;
  const int B = in_sizes[0] / (TT * IN);        // 4096
  const int grid = (B + NB - 1) / NB;           // 16 batches per 64-thread wave
  rnn_mfma<<<grid, 64, 0, stream>>>(feature, W_ih, W_hh, b_ih, b_hh, out, B);
}

// Round 8
// 209.676 us; speedup vs baseline: 1.3758x; 1.0982x over previous
//
#include <hip/hip_runtime.h>
#include <cstddef>

// RNN: h_t = tanh(x_t @ W_ih^T + b_ih + h_{t-1} @ W_hh^T + b_hh), return h_T.
// B=4096, T=512, IN=15, H=20.
//
// R5 post-mortem: no-LDS depth-8 register x-pipeline worked (155.6->97.8us,
// LDS=0, conflicts=0) but 458 cyc/step remains vs ~250 model. 1 wave/SIMD
// => wall = 512 * chain latency; the chain still carried 8 exp + 8 rcp +
// 8 add + 8 fma + 6 pack per lane while only 20/32 D-rows are real (H=20).
//
// R6: shrink the chain.
//  (a) pi-packed K-slots: B slot k=8G+i holds h[5G+i] (i=0..4), i=5..7 dead
//      (zero A columns). Rows: sigma_P(m)=5(m>>2)+(m&3) -> D(P) slot (G,r)
//      = z[5G+r]; sigma_Q(m)=5(m>>2)+4 -> D(Q) slot (G,0) = z[5G+4].
//      Wave-uniform tanh work: 5 per lane (aP[0..3], aQ[0]) instead of 8.
//  (b) carry u = 1/(1+2^z) instead of h = 1-2u: fold -2 into A (-2*K2*Whh)
//      and +1 into bias (+K2*rowsum Whh). Chain per element: exp2 -> add ->
//      rcp -> pack (fma stage deleted). h0=0 => u0=0.5 (rowsum cancels).
//  x path unchanged: per-lane global_load_dwordx4 into depth-8 register
//  pipeline, consumed 8 steps later (counted vmcnt, no drains); cx MFMAs
//  off-chain one step ahead. Weights/bias pre-scaled by K2=2*log2(e).
// Chain/step ~ mfma_lat + exp + add + rcp + pk ~ 100-150 cy -> 60-75us.
// (R7 resubmit unchanged: Round 7 was an infra failure -- container died
// before compile/run, same as Round 5 which ran fine on resubmission.)

typedef float f4 __attribute__((ext_vector_type(4)));
typedef float g4 __attribute__((ext_vector_type(4), aligned(4)));
typedef _Float16 h2 __attribute__((ext_vector_type(2)));
typedef _Float16 v4h __attribute__((ext_vector_type(4)));
typedef _Float16 v8h __attribute__((ext_vector_type(8)));
typedef __fp16 p2 __attribute__((ext_vector_type(2)));

#define TT 512
#define IN 15
#define HD 20
#define NB 16  // batches per wave

__device__ __forceinline__ float fexp2(float x) {
#if __has_builtin(__builtin_amdgcn_exp2f)
  return __builtin_amdgcn_exp2f(x);  // native v_exp_f32
#else
  return exp2f(x);
#endif
}
__device__ __forceinline__ h2 pk2(float a, float b) {
  p2 r = __builtin_amdgcn_cvt_pkrtz(a, b);
  return __builtin_bit_cast(h2, r);
}
__device__ __forceinline__ v4h cat4(h2 a, h2 b) {
  return __builtin_shufflevector(a, b, 0, 1, 2, 3);
}
__device__ __forceinline__ v8h cat8(v4h a, v4h b) {
  return __builtin_shufflevector(a, b, 0, 1, 2, 3, 4, 5, 6, 7);
}

__global__ __launch_bounds__(64) void rnn_mfma(
    const float* __restrict__ feature, const float* __restrict__ W_ih,
    const float* __restrict__ W_hh, const float* __restrict__ b_ih,
    const float* __restrict__ b_hh, float* __restrict__ out, int B) {
  const int l = threadIdx.x;   // 0..63
  const int G = l >> 4;        // k-group 0..3
  const int mf = l & 15;       // A fragment row / B,D batch column
  const int b0 = blockIdx.x * NB;

  const float K2 = 2.8853900817779268f;  // 2*log2(e)

  // --- row assignments (pi-packing) ---------------------------------
  const int jP = 5 * (mf >> 2) + (mf & 3);  // sigma_P(mf), < 20 always
  const int jQ = 5 * (mf >> 2) + 4;         // sigma_Q(mf), < 20 always

  // Recurrence A-fragments: A[m][k=8G+i] = -2*K2*Whh[sigma(m)][5G+i], i<5.
  v8h AhhP, AhhQ;
#pragma unroll
  for (int i = 0; i < 8; ++i) {
    const int k = 5 * G + i;  // h index carried in slot i (valid i<5)
    const float wP = (i < 5) ? -2.f * K2 * W_hh[jP * HD + k] : 0.f;
    const float wQ = (i < 5) ? -2.f * K2 * W_hh[jQ * HD + k] : 0.f;
    AhhP[i] = (_Float16)wP;
    AhhQ[i] = (_Float16)wQ;
  }
  // x-projection A (16x16x16, lane k-window = k0..k0+3). G=3 shifts to
  // k0=11 (avoids 4B OOB at the last row); duplicate k=11 zeroed in G=2.
  const int k0 = (G < 3) ? 4 * G : 11;
  v4h AihP, AihQ;
#pragma unroll
  for (int i = 0; i < 4; ++i) {
    const int k = k0 + i;
    const bool dup = (G == 2 && i == 3);  // k=11 owned by G=3
    AihP[i] = (_Float16)((k < IN && !dup) ? K2 * W_ih[jP * IN + k] : 0.f);
    AihQ[i] = (_Float16)((k < IN && !dup) ? K2 * W_ih[jQ * IN + k] : 0.f);
  }
  // bias as C fragments: D slot (G,r): P -> j=5G+r, Q -> j=5G+4 (all r).
  // Includes +K2*rowsum(Whh[j]) from the h = 1-2u fold.
  f4 biasP, biasQ;
#pragma unroll
  for (int r = 0; r < 4; ++r) {
    const int jp = 5 * G + r, jq = 5 * G + 4;
    float rsP = 0.f, rsQ = 0.f;
#pragma unroll
    for (int k = 0; k < HD; ++k) {
      rsP += W_hh[jp * HD + k];
      rsQ += W_hh[jq * HD + k];
    }
    biasP[r] = K2 * (b_ih[jp] + b_hh[jp] + rsP);
    biasQ[r] = K2 * (b_ih[jq] + b_hh[jq] + rsQ);
  }

  // --- per-lane x fragment source: 16B at feature[b][t][k0] ----------
  const int b = min(b0 + mf, B - 1);
  const float* xbase = feature + (size_t)b * TT * IN + k0;
  auto load_x = [&](int t) -> g4 {
    return *(const g4*)(xbase + (size_t)t * IN);
  };

  // depth-8 register pipeline (static indices only under full unroll).
  g4 XR[8];
#pragma unroll
  for (int s = 1; s <= 8; ++s) XR[s & 7] = load_x(s);

  // prologue: cx(0)
  g4 x0 = load_x(0);
  v4h X0 = cat4(pk2(x0.x, x0.y), pk2(x0.z, x0.w));
  f4 cxPc = __builtin_amdgcn_mfma_f32_16x16x16f16(AihP, X0, biasP, 0, 0, 0);
  f4 cxQc = __builtin_amdgcn_mfma_f32_16x16x16f16(AihQ, X0, biasQ, 0, 0, 0);

  // B-fragment carries u; h0 = 0 <=> u0 = 0.5 in live slots (i<5).
  v8h Bh;
#pragma unroll
  for (int i = 0; i < 8; ++i) Bh[i] = (_Float16)((i < 5) ? 0.5f : 0.f);

  float uP[4], uQ0 = 0.5f;  // last u values -> epilogue h = 1-2u
#pragma unroll
  for (int r = 0; r < 4; ++r) uP[r] = 0.5f;

  const h2 zero2 = {(_Float16)0.f, (_Float16)0.f};

  for (int t = 0; t < TT; t += 8) {
#pragma unroll
    for (int u = 0; u < 8; ++u) {
      // --- recurrence chain: mfma -> u=rcp(1+2^z) -> pack -> mfma ---
      f4 aP = __builtin_amdgcn_mfma_f32_16x16x32_f16(AhhP, Bh, cxPc, 0, 0, 0);
      f4 aQ = __builtin_amdgcn_mfma_f32_16x16x32_f16(AhhQ, Bh, cxQc, 0, 0, 0);
      // off-chain: cx(t+u+1) from pipeline slot (loaded 8 steps ago)
      const int s = (u + 1) & 7;
      g4 xr = XR[s];
      v4h Xn = cat4(pk2(xr.x, xr.y), pk2(xr.z, xr.w));
      cxPc = __builtin_amdgcn_mfma_f32_16x16x16f16(AihP, Xn, biasP, 0, 0, 0);
      cxQc = __builtin_amdgcn_mfma_f32_16x16x16f16(AihQ, Xn, biasQ, 0, 0, 0);
      // refill slot with x(t+u+9) (clamped tail loads are harmless)
      const int tn = t + u + 9;
      XR[s] = load_x(tn < TT ? tn : TT - 1);
      // u = 1/(1+2^z): only 5 live elements (pi-packing)
#pragma unroll
      for (int r = 0; r < 4; ++r)
        uP[r] = __builtin_amdgcn_rcpf(1.f + fexp2(aP[r]));
      uQ0 = __builtin_amdgcn_rcpf(1.f + fexp2(aQ[0]));
      Bh = cat8(cat4(pk2(uP[0], uP[1]), pk2(uP[2], uP[3])),
                cat4(pk2(uQ0, 0.f), zero2));
    }
  }

  // epilogue: h_T = 1 - 2u. Lane (G,mf): P r -> j=5G+r, Q -> j=5G+4,
  // batch = b0 + mf. All j < 20 by construction.
  const int batch = b0 + mf;
  if (batch < B) {
    float* orow = out + (size_t)batch * HD;
#pragma unroll
    for (int r = 0; r < 4; ++r) orow[5 * G + r] = 1.f - 2.f * uP[r];
    orow[5 * G + 4] = 1.f - 2.f * uQ0;
  }
}

extern "C" void kernel_launch(void* const* d_in, const int* in_sizes, int n_in,
                              void* d_out, int out_size, void* d_ws, size_t ws_size,
                              hipStream_t stream) {
  const float* feature = (const float*)d_in[0];
  const float* W_ih    = (const float*)d_in[1];
  const float* W_hh    = (const float*)d_in[2];
  const float* b_ih    = (const float*)d_in[3];
  const float* b_hh    = (const float*)d_in[4];
  float* out = (float*)d_out;
  const int B = in_sizes[0] / (TT * IN);        // 4096
  const int grid = (B + NB - 1) / NB;           // 16 batches per 64-thread wave
  rnn_mfma<<<grid, 64, 0, stream>>>(feature, W_ih, W_hh, b_ih, b_hh, out, B);
}